// Round 26
// baseline (124.382 us; speedup 1.0000x reference)
//
#include <hip/hip_runtime.h>
#include <hip/hip_bf16.h>
#include <math.h>

#define BTOT 16384

typedef __attribute__((ext_vector_type(8))) short short8;
typedef __attribute__((ext_vector_type(4))) float f32x4;
typedef __attribute__((ext_vector_type(16))) float f32x16;

__device__ __forceinline__ float selu_fast(float x) {
  const float scale = 1.0507009873554805f;
  const float alpha = 1.6732632423543772f;
  float e = exp2f(x * 1.44269504088896f);     // v_exp_f32; err ~1e-7 abs
  float neg = alpha * (e - 1.0f);
  return scale * (x > 0.0f ? x : neg);
}

__device__ __forceinline__ unsigned int bf16u(float x) {
  __hip_bfloat16 h = __float2bfloat16(x);     // RNE, matches prior rounds
  return (unsigned int)*reinterpret_cast<unsigned short*>(&h);
}

// ---------------- prep: W -> fragment-linear bf16 (B-operand order, r16) -----
__global__ __launch_bounds__(256) void prep_kernel(
    const float* __restrict__ W0, unsigned int* __restrict__ Wf0,
    const float* __restrict__ W1, unsigned int* __restrict__ Wf1,
    const float* __restrict__ W2, unsigned int* __restrict__ Wf2,
    const float* __restrict__ W3, unsigned int* __restrict__ Wf3,
    const float* __restrict__ Wout, unsigned int* __restrict__ WfO) {
  __shared__ float tile[32][33];
  const int t = blockIdx.x;
  const float* W;
  unsigned int* Wf;
  int N, TS, kbt, nbt;
  if (t < 16)        { W = W0;   Wf = Wf0; N = 512;  TS = 1;  kbt = 0;       nbt = t; }
  else if (t < 272)  { int u = t - 16;  W = W1;   Wf = Wf1; N = 512;  TS = 16; kbt = u & 15; nbt = u >> 4; }
  else if (t < 528)  { int u = t - 272; W = W2;   Wf = Wf2; N = 512;  TS = 16; kbt = u & 15; nbt = u >> 4; }
  else if (t < 784)  { int u = t - 528; W = W3;   Wf = Wf3; N = 512;  TS = 16; kbt = u & 15; nbt = u >> 4; }
  else               { int u = t - 784; W = Wout; Wf = WfO; N = 1024; TS = 16; kbt = u & 15; nbt = u >> 4; }
  const int kb32 = kbt * 32, nb32 = nbt * 32;
  const int tx = threadIdx.x & 31, ty = threadIdx.x >> 5;
  #pragma unroll
  for (int rr = 0; rr < 4; ++rr) {
    int kl = ty + rr * 8;
    tile[kl][tx] = W[(size_t)(kb32 + kl) * N + nb32 + tx];
  }
  __syncthreads();
  const int cbb = threadIdx.x >> 7;
  const int rest = threadIdx.x & 127;
  const int l = rest >> 1;
  const int wjh = rest & 1;
  const int cb = 2 * nbt + cbb;
  unsigned int wv[2];
  #pragma unroll
  for (int m = 0; m < 2; ++m) {
    int wj = wjh * 2 + m;
    int kl = (l >> 4) * 8 + wj * 2;
    int nl = cbb * 16 + (l & 15);
    wv[m] = bf16u(tile[kl][nl]) | (bf16u(tile[kl + 1][nl]) << 16);
  }
  size_t widx = ((size_t)(cb * TS + kbt) * 64 + l) * 4 + wjh * 2;
  *reinterpret_cast<uint2*>(Wf + widx) = make_uint2(wv[0], wv[1]);
}

// ---------------- fused MLP: 32 rows/block, 256 threads (4 waves) ------------
// r25 lever continued: 256-thread blocks raise the per-CU block-pack cap
// (thread-cap 8, LDS-cap 4) vs 512-thread (~3 packed). Same K-loop schedule
// (depth-1 under unroll 2), same 512 blocks (W L2 traffic unchanged).
// Hidden: N=512 = 4 passes of 4 waves; in-place safety via acc[4][2][2]
// (all static indices) accumulated before ONE barrier, then 4 epilogues.
template<int K>
__device__ __forceinline__ void run_hidden(
    const short8* __restrict__ Wf,
    const float* __restrict__ Wlast,
    const float* __restrict__ bias,
    char* actBuf,
    const float* tsl, int w, int lane) {
  constexpr int TS = K / 32;
  constexpr int NKB = K / 8;
  const int colloc = lane & 15, kg = lane >> 4;
  int rbyte[2], rmask[2];
  #pragma unroll
  for (int i = 0; i < 2; ++i) {
    int r = i * 16 + colloc;          // A-frag row (verified bijection)
    rbyte[i] = r * 1024;
    rmask[i] = r & (NKB - 1);
  }
  f32x4 acc[4][2][2] = {};
  #pragma unroll
  for (int pass = 0; pass < 4; ++pass) {
    const int wb = pass * 128 + w * 32;
    const int cb0 = wb >> 4;
    short8 acur[2], bcur0, bcur1;
    bcur0 = Wf[(size_t)(cb0 * TS) * 64 + lane];
    bcur1 = Wf[(size_t)((cb0 + 1) * TS) * 64 + lane];
    #pragma unroll
    for (int i = 0; i < 2; ++i)
      acur[i] = *reinterpret_cast<const short8*>(actBuf + rbyte[i] + ((kg ^ rmask[i]) * 16));
    #pragma unroll 2
    for (int t = 0; t < TS; ++t) {
      const int tn = (t + 1 < TS) ? (t + 1) : t;
      short8 bnx0 = Wf[(size_t)(cb0 * TS + tn) * 64 + lane];
      short8 bnx1 = Wf[(size_t)((cb0 + 1) * TS + tn) * 64 + lane];
      short8 anx[2];
      #pragma unroll
      for (int i = 0; i < 2; ++i)
        anx[i] = *reinterpret_cast<const short8*>(actBuf + rbyte[i] + (((tn * 4 + kg) ^ rmask[i]) * 16));
      #pragma unroll
      for (int i = 0; i < 2; ++i) {
        acc[pass][i][0] = __builtin_amdgcn_mfma_f32_16x16x32_bf16(acur[i], bcur0, acc[pass][i][0], 0, 0, 0);
        acc[pass][i][1] = __builtin_amdgcn_mfma_f32_16x16x32_bf16(acur[i], bcur1, acc[pass][i][1], 0, 0, 0);
      }
      #pragma unroll
      for (int i = 0; i < 2; ++i) acur[i] = anx[i];
      bcur0 = bnx0; bcur1 = bnx1;
    }
  }
  // ALL reads of actBuf complete block-wide before ANY write
  __syncthreads();
  #pragma unroll
  for (int pass = 0; pass < 4; ++pass) {
    const int wb = pass * 128 + w * 32;
    float wl[2], bb[2];
    #pragma unroll
    for (int c = 0; c < 2; ++c) {
      int col = wb + c * 16 + colloc;
      wl[c] = Wlast[col];
      bb[c] = bias[col];
    }
    #pragma unroll
    for (int i = 0; i < 2; ++i) {
      #pragma unroll
      for (int e = 0; e < 4; ++e) {
        int row = i * 16 + kg * 4 + e;   // D-layout row (verified)
        float tv = tsl[row];
        #pragma unroll
        for (int c = 0; c < 2; ++c) {
          float v = acc[pass][i][c][e] + tv * wl[c] + bb[c];
          v = selu_fast(v);
          int col = wb + c * 16 + colloc;
          int off = row * 1024 + (((col >> 3) ^ (row & 63)) * 16) + (col & 7) * 2;
          *reinterpret_cast<unsigned short*>(actBuf + off) = (unsigned short)bf16u(v);
        }
      }
    }
  }
}

// final layer: N=1024, 8 passes of 4 waves, clip + pair-pack global store
__device__ __forceinline__ void run_out(
    const short8* __restrict__ Wf,
    const float* __restrict__ Wlast,
    const float* __restrict__ bias,
    const char* actBuf,
    __hip_bfloat16* __restrict__ gOut, int rowbase,
    const float* tsl, int w, int lane) {
  constexpr int K = 512, TS = K / 32, NKB = K / 8;
  const int colloc = lane & 15, kg = lane >> 4;
  int rbyte[2], rmask[2];
  #pragma unroll
  for (int i = 0; i < 2; ++i) {
    int r = i * 16 + colloc;
    rbyte[i] = r * 1024;
    rmask[i] = r & (NKB - 1);
  }
  #pragma unroll 1
  for (int pass = 0; pass < 8; ++pass) {
    const int wb = pass * 128 + w * 32;
    const int cb0 = wb >> 4;
    f32x4 acc[2][2] = {};
    short8 acur[2], bcur0, bcur1;
    bcur0 = Wf[(size_t)(cb0 * TS) * 64 + lane];
    bcur1 = Wf[(size_t)((cb0 + 1) * TS) * 64 + lane];
    #pragma unroll
    for (int i = 0; i < 2; ++i)
      acur[i] = *reinterpret_cast<const short8*>(actBuf + rbyte[i] + ((kg ^ rmask[i]) * 16));
    #pragma unroll 2
    for (int t = 0; t < TS; ++t) {
      const int tn = (t + 1 < TS) ? (t + 1) : t;
      short8 bnx0 = Wf[(size_t)(cb0 * TS + tn) * 64 + lane];
      short8 bnx1 = Wf[(size_t)((cb0 + 1) * TS + tn) * 64 + lane];
      short8 anx[2];
      #pragma unroll
      for (int i = 0; i < 2; ++i)
        anx[i] = *reinterpret_cast<const short8*>(actBuf + rbyte[i] + (((tn * 4 + kg) ^ rmask[i]) * 16));
      #pragma unroll
      for (int i = 0; i < 2; ++i) {
        acc[i][0] = __builtin_amdgcn_mfma_f32_16x16x32_bf16(acur[i], bcur0, acc[i][0], 0, 0, 0);
        acc[i][1] = __builtin_amdgcn_mfma_f32_16x16x32_bf16(acur[i], bcur1, acc[i][1], 0, 0, 0);
      }
      #pragma unroll
      for (int i = 0; i < 2; ++i) acur[i] = anx[i];
      bcur0 = bnx0; bcur1 = bnx1;
    }
    float wl[2], bb[2];
    #pragma unroll
    for (int c = 0; c < 2; ++c) {
      int col = wb + c * 16 + colloc;
      wl[c] = Wlast[col];
      bb[c] = bias[col];
    }
    #pragma unroll
    for (int i = 0; i < 2; ++i) {
      #pragma unroll
      for (int e = 0; e < 4; ++e) {
        int row = i * 16 + kg * 4 + e;
        float tv = tsl[row];
        #pragma unroll
        for (int c = 0; c < 2; ++c) {
          float v = acc[i][c][e] + tv * wl[c] + bb[c];
          v = fminf(fmaxf(v, -20.f), 20.f);
          float o = __shfl_xor(v, 1);
          unsigned int me = bf16u(v), ot = bf16u(o);
          unsigned int pw = (colloc & 1) ? ((me << 16) | ot) : ((ot << 16) | me);
          const bool iwrite = ((colloc & 1) == (e >> 1));
          int col0 = wb + c * 16 + (colloc & ~1);
          if (iwrite) {
            size_t off = (size_t)(rowbase + row) * 1024 + col0;
            *reinterpret_cast<unsigned int*>(
                reinterpret_cast<char*>(gOut) + off * 2) = pw;
          }
        }
      }
    }
  }
}

__global__ __launch_bounds__(256) void fused_mlp_kernel(
    const float* __restrict__ p,
    const float* __restrict__ tvec,
    const short8* Wf0, const short8* Wf1, const short8* Wf2,
    const short8* Wf3, const short8* WfO,
    const float* W0l, const float* b0,
    const float* W1l, const float* b1,
    const float* W2l, const float* b2,
    const float* W3l, const float* b3,
    const float* WOl, const float* bO,
    __hip_bfloat16* __restrict__ flatb) {
  __shared__ char buf[32768];
  __shared__ float tsl[32];
  const int tid = threadIdx.x;
  const int w = tid >> 6, lane = tid & 63;
  const int rowbase = blockIdx.x * 32;

  if (tid < 32) tsl[tid] = tvec[rowbase + tid];
  {  // stage p -> buf (K=32 layout, NKB=4 swizzle); 256 threads cover all
    const int r = tid >> 3, g = tid & 7;
    float4 v = *reinterpret_cast<const float4*>(p + (size_t)(rowbase + r) * 32 + g * 4);
    unsigned int lo = bf16u(v.x) | (bf16u(v.y) << 16);
    unsigned int hi = bf16u(v.z) | (bf16u(v.w) << 16);
    int off = r * 1024 + (((g >> 1) ^ (r & 3)) * 16) + (g & 1) * 8;
    *reinterpret_cast<uint2*>(buf + off) = make_uint2(lo, hi);
  }
  __syncthreads();

  run_hidden<32>(Wf0, W0l, b0, buf, tsl, w, lane);
  __syncthreads();
  run_hidden<512>(Wf1, W1l, b1, buf, tsl, w, lane);
  __syncthreads();
  run_hidden<512>(Wf2, W2l, b2, buf, tsl, w, lane);
  __syncthreads();
  run_hidden<512>(Wf3, W3l, b3, buf, tsl, w, lane);
  __syncthreads();
  run_out(WfO, WOl, bO, buf, flatb, rowbase, tsl, w, lane);
}

// ---------------- expm: transposed chain, 2 matrices/wave ILP (r11, frozen) --
#define WAITLDS asm volatile("s_waitcnt lgkmcnt(0)" ::: "memory")

__device__ __forceinline__ unsigned int bf16r(float x) {
  return (__float_as_uint(x) + 0x8000u) >> 16;
}

__device__ __forceinline__ void d2b_lean(const float (&X)[16], int G, short8 (&bfr)[2]) {
  float rcv[8];
  #pragma unroll
  for (int j = 0; j < 8; ++j) {
    const int hp = j >> 2, tt = j & 3;
    float snd = G ? X[8 * hp + tt] : X[8 * hp + 4 + tt];
    rcv[j] = __shfl_xor(snd, 32);
  }
  #pragma unroll
  for (int h = 0; h < 2; ++h) {
    float r8v[8];
    #pragma unroll
    for (int j2 = 0; j2 < 8; ++j2) {
      if (j2 < 4) r8v[j2] = G ? rcv[4 * h + j2] : X[8 * h + j2];
      else        r8v[j2] = G ? X[8 * h + j2] : rcv[4 * h + j2 - 4];
    }
    union { short8 s8; unsigned int u[4]; } bu;
    #pragma unroll
    for (int j = 0; j < 4; ++j)
      bu.u[j] = bf16r(r8v[2 * j]) | (bf16r(r8v[2 * j + 1]) << 16);
    bfr[h] = bu.s8;
  }
}

__device__ __forceinline__ void d2b_split_lean(const float (&X)[16], int G,
                                               short8 (&bh)[2], short8 (&bl)[2]) {
  float rcv[8];
  #pragma unroll
  for (int j = 0; j < 8; ++j) {
    const int hp = j >> 2, tt = j & 3;
    float snd = G ? X[8 * hp + tt] : X[8 * hp + 4 + tt];
    rcv[j] = __shfl_xor(snd, 32);
  }
  #pragma unroll
  for (int h = 0; h < 2; ++h) {
    float r8v[8];
    #pragma unroll
    for (int j2 = 0; j2 < 8; ++j2) {
      if (j2 < 4) r8v[j2] = G ? rcv[4 * h + j2] : X[8 * h + j2];
      else        r8v[j2] = G ? X[8 * h + j2] : rcv[4 * h + j2 - 4];
    }
    union { short8 s8; unsigned int u[4]; } uh, ul;
    #pragma unroll
    for (int j = 0; j < 4; ++j) {
      unsigned int b0 = __float_as_uint(r8v[2 * j]) & 0xFFFF0000u;
      unsigned int b1 = __float_as_uint(r8v[2 * j + 1]) & 0xFFFF0000u;
      float l0 = r8v[2 * j] - __uint_as_float(b0);
      float l1 = r8v[2 * j + 1] - __uint_as_float(b1);
      uh.u[j] = (b0 >> 16) | b1;
      ul.u[j] = bf16r(l0) | (bf16r(l1) << 16);
    }
    bh[h] = uh.s8;
    bl[h] = ul.s8;
  }
}

union u4s8 { uint4 u4; short8 s8; unsigned int u[4]; };

__global__ __launch_bounds__(256) void expm_ilp2_kernel(
    const __hip_bfloat16* __restrict__ flat,
    const float* __restrict__ q,
    const float* __restrict__ dtp,
    float* __restrict__ out_q,
    float* __restrict__ out_dlogp) {
  __shared__ __align__(16) unsigned int SL[4][2][16][33];
  const int tid = threadIdx.x;
  const int w = tid >> 6, lane = tid & 63;
  const int C = lane & 31, G = lane >> 5;
  const int m0 = blockIdx.x * 8 + w * 2;
  const float dt = dtp[0];

  u4s8 t0[2], t1[2];
  float E[2][16];
  float uu[2];
  int nv[2];

  #pragma unroll
  for (int mm = 0; mm < 2; ++mm) {
    const int m = m0 + mm;
    const uint4* fm = reinterpret_cast<const uint4*>(flat + (size_t)m * 1024);
    uint4 v0 = fm[lane];
    uint4 v1 = fm[lane + 64];
    {
      const int r0 = lane >> 2, kpb = (lane & 3) * 4;
      SL[w][mm][kpb + 0][r0] = v0.x; SL[w][mm][kpb + 1][r0] = v0.y;
      SL[w][mm][kpb + 2][r0] = v0.z; SL[w][mm][kpb + 3][r0] = v0.w;
      SL[w][mm][kpb + 0][r0 + 16] = v1.x; SL[w][mm][kpb + 1][r0 + 16] = v1.y;
      SL[w][mm][kpb + 2][r0 + 16] = v1.z; SL[w][mm][kpb + 3][r0 + 16] = v1.w;
    }
    {
      const char* base = reinterpret_cast<const char*>(flat) + (size_t)m * 2048 + C * 64 + G * 16;
      t0[mm].u4 = *reinterpret_cast<const uint4*>(base);
      t1[mm].u4 = *reinterpret_cast<const uint4*>(base + 32);
    }

    float sa = 0.f;
    #pragma unroll
    for (int i = 0; i < 4; ++i) {
      sa += fabsf(__uint_as_float(t0[mm].u[i] << 16)) + fabsf(__uint_as_float(t0[mm].u[i] & 0xFFFF0000u));
      sa += fabsf(__uint_as_float(t1[mm].u[i] << 16)) + fabsf(__uint_as_float(t1[mm].u[i] & 0xFFFF0000u));
    }
    sa += __shfl_xor(sa, 32);
    float nrm = sa;
    #pragma unroll
    for (int off = 1; off < 32; off <<= 1) nrm = fmaxf(nrm, __shfl_xor(nrm, off));

    int s = 0;
    float anrm = dt * nrm;
    if (anrm > 1.0f) {
      s = (int)ceilf(log2f(anrm));
      s = s < 1 ? 1 : (s > 6 ? 6 : s);
    }
    nv[mm] = 1 << s;
    const float u = dt * exp2f(-(float)s);
    uu[mm] = u;

    unsigned int pt0[4], pt1[4];
    #pragma unroll
    for (int d = 0; d < 4; ++d) {
      pt0[d] = (unsigned int)__shfl_xor((int)t0[mm].u[d], 32);
      pt1[d] = (unsigned int)__shfl_xor((int)t1[mm].u[d], 32);
    }
    float tr = 0.f;
    #pragma unroll
    for (int j = 0; j < 4; ++j) {
      #pragma unroll
      for (int e2 = 0; e2 < 4; ++e2) {
        const int i = 4 * j + e2;
        const int rd = e2 + 8 * j + 4 * G;
        const bool own = ((j & 1) == G);
        unsigned int dwO, dwP;
        if ((e2 >> 1) == 0) {
          dwO = G ? ((j < 2) ? t0[mm].u[2] : t1[mm].u[2]) : ((j < 2) ? t0[mm].u[0] : t1[mm].u[0]);
          dwP = G ? ((j < 2) ? pt0[2] : pt1[2]) : ((j < 2) ? pt0[0] : pt1[0]);
        } else {
          dwO = G ? ((j < 2) ? t0[mm].u[3] : t1[mm].u[3]) : ((j < 2) ? t0[mm].u[1] : t1[mm].u[1]);
          dwP = G ? ((j < 2) ? pt0[3] : pt1[3]) : ((j < 2) ? pt0[1] : pt1[1]);
        }
        unsigned int dw = own ? dwO : dwP;
        unsigned int h16 = (e2 & 1) ? (dw >> 16) : (dw & 0xFFFFu);
        float mv = __uint_as_float(h16 << 16);
        float dI = (rd == C) ? 1.0f : 0.0f;
        E[mm][i] = dI + u * mv;
        tr += dI * mv;
      }
    }
    #pragma unroll
    for (int off = 1; off < 64; off <<= 1) tr += __shfl_xor(tr, off);
    if (lane == 0) out_dlogp[m] = dt * tr;
  }

  WAITLDS;

  short8 Mfr[2][2];
  {
    const unsigned int selpat = (C & 1) ? 0x07060302u : 0x05040100u;
    #pragma unroll
    for (int mm = 0; mm < 2; ++mm) {
      #pragma unroll
      for (int h = 0; h < 2; ++h) {
        unsigned int rr[8];
        #pragma unroll
        for (int e = 0; e < 8; ++e) rr[e] = SL[w][mm][C >> 1][16 * h + 8 * G + e];
        union { short8 s8; unsigned int u[4]; } mu;
        #pragma unroll
        for (int j = 0; j < 4; ++j)
          mu.u[j] = __builtin_amdgcn_perm(rr[2 * j + 1], rr[2 * j], selpat);
        Mfr[mm][h] = mu.s8;
      }
    }
  }

  float Qc[2][16];
  float ck[2];
  #pragma unroll
  for (int mm = 0; mm < 2; ++mm) {
    ck[mm] = uu[mm] * uu[mm] * 0.5f;
    f32x16 acc = {};
    acc = __builtin_amdgcn_mfma_f32_32x32x16_bf16(Mfr[mm][0], t0[mm].s8, acc, 0, 0, 0);
    acc = __builtin_amdgcn_mfma_f32_32x32x16_bf16(Mfr[mm][1], t1[mm].s8, acc, 0, 0, 0);
    #pragma unroll
    for (int i = 0; i < 16; ++i) { Qc[mm][i] = acc[i]; E[mm][i] += ck[mm] * acc[i]; }
  }
  #pragma unroll
  for (int k = 3; k <= 6; ++k) {
    #pragma unroll
    for (int mm = 0; mm < 2; ++mm) {
      short8 bfr[2];
      d2b_lean(Qc[mm], G, bfr);
      f32x16 acc = {};
      acc = __builtin_amdgcn_mfma_f32_32x32x16_bf16(Mfr[mm][0], bfr[0], acc, 0, 0, 0);
      acc = __builtin_amdgcn_mfma_f32_32x32x16_bf16(Mfr[mm][1], bfr[1], acc, 0, 0, 0);
      ck[mm] *= uu[mm] * (1.0f / (float)k);
      #pragma unroll
      for (int i = 0; i < 16; ++i) { Qc[mm][i] = acc[i]; E[mm][i] += ck[mm] * acc[i]; }
    }
  }

  short8 beh[2][2], bel[2][2];
  #pragma unroll
  for (int mm = 0; mm < 2; ++mm)
    d2b_split_lean(E[mm], G, beh[mm], bel[mm]);

  float qv[2];
  qv[0] = q[(size_t)m0 * 32 + C];
  qv[1] = q[(size_t)(m0 + 1) * 32 + C];
  const int nvmax = nv[0] > nv[1] ? nv[0] : nv[1];
  #pragma unroll 1
  for (int it = 0; it < nvmax; ++it) {
    #pragma unroll
    for (int mm = 0; mm < 2; ++mm) {
      unsigned int hb = __float_as_uint(qv[mm]) & 0xFFFF0000u;
      float lof = qv[mm] - __uint_as_float(hb);
      unsigned int pw = (hb >> 16) | (bf16r(lof) << 16);
      short8 vh[2], vl[2];
      #pragma unroll
      for (int h = 0; h < 2; ++h) {
        unsigned int g[8];
        #pragma unroll
        for (int e = 0; e < 8; ++e)
          g[e] = (unsigned int)__shfl((int)pw, 16 * h + 8 * G + e);
        union { short8 s8; unsigned int u[4]; } uh, ul;
        #pragma unroll
        for (int j = 0; j < 4; ++j) {
          uh.u[j] = __builtin_amdgcn_perm(g[2 * j + 1], g[2 * j], 0x05040100u);
          ul.u[j] = __builtin_amdgcn_perm(g[2 * j + 1], g[2 * j], 0x07060302u);
        }
        vh[h] = uh.s8;
        vl[h] = ul.s8;
      }
      f32x16 acc = {};
      acc = __builtin_amdgcn_mfma_f32_32x32x16_bf16(vh[0], beh[mm][0], acc, 0, 0, 0);
      acc = __builtin_amdgcn_mfma_f32_32x32x16_bf16(vh[1], beh[mm][1], acc, 0, 0, 0);
      acc = __builtin_amdgcn_mfma_f32_32x32x16_bf16(vl[0], beh[mm][0], acc, 0, 0, 0);
      acc = __builtin_amdgcn_mfma_f32_32x32x16_bf16(vl[1], beh[mm][1], acc, 0, 0, 0);
      acc = __builtin_amdgcn_mfma_f32_32x32x16_bf16(vh[0], bel[mm][0], acc, 0, 0, 0);
      acc = __builtin_amdgcn_mfma_f32_32x32x16_bf16(vh[1], bel[mm][1], acc, 0, 0, 0);
      qv[mm] = (it < nv[mm]) ? acc[0] : qv[mm];
    }
  }
  if (G == 0) {
    out_q[(size_t)m0 * 32 + C] = qv[0];
    out_q[(size_t)(m0 + 1) * 32 + C] = qv[1];
  }
}

extern "C" void kernel_launch(void* const* d_in, const int* in_sizes, int n_in,
                              void* d_out, int out_size, void* d_ws, size_t ws_size,
                              hipStream_t stream) {
  const float* q    = (const float*)d_in[0];
  const float* p    = (const float*)d_in[1];
  const float* t    = (const float*)d_in[2];
  const float* dt   = (const float*)d_in[3];
  const float* W0   = (const float*)d_in[4];
  const float* b0   = (const float*)d_in[5];
  const float* W1   = (const float*)d_in[6];
  const float* b1   = (const float*)d_in[7];
  const float* W2   = (const float*)d_in[8];
  const float* b2   = (const float*)d_in[9];
  const float* W3   = (const float*)d_in[10];
  const float* b3   = (const float*)d_in[11];
  const float* Wout = (const float*)d_in[12];
  const float* bout = (const float*)d_in[13];

  // ws layout: flatb (bf16 B*1024), then fragment-linear weights (u32)
  char* ws = (char*)d_ws;
  __hip_bfloat16* flatb = (__hip_bfloat16*)ws;              // 32 MB
  unsigned int* Wf0 = (unsigned int*)(ws + (size_t)BTOT * 1024 * 2);
  unsigned int* Wf1 = Wf0 + 32 * 512 / 2;
  unsigned int* Wf2 = Wf1 + 512 * 512 / 2;
  unsigned int* Wf3 = Wf2 + 512 * 512 / 2;
  unsigned int* WfO = Wf3 + 512 * 512 / 2;

  prep_kernel<<<1296, 256, 0, stream>>>(W0, Wf0, W1, Wf1, W2, Wf2, W3, Wf3,
                                        Wout, WfO);

  fused_mlp_kernel<<<512, 256, 0, stream>>>(
      p, t,
      (const short8*)Wf0, (const short8*)Wf1, (const short8*)Wf2,
      (const short8*)Wf3, (const short8*)WfO,
      W0 + 32 * 512, b0, W1 + 512 * 512, b1, W2 + 512 * 512, b2,
      W3 + 512 * 512, b3, Wout + 512 * 1024, bout, flatb);

  float* out_q     = (float*)d_out;
  float* out_dlogp = out_q + (size_t)BTOT * 32;
  expm_ilp2_kernel<<<BTOT / 8, 256, 0, stream>>>(flatb, q, dt, out_q, out_dlogp);
}

// Round 27
// 106.028 us; speedup vs baseline: 1.1731x; 1.1731x over previous
//
#include <hip/hip_runtime.h>
#include <hip/hip_bf16.h>
#include <math.h>

#define BTOT 16384

typedef __attribute__((ext_vector_type(8))) short short8;
typedef __attribute__((ext_vector_type(4))) float f32x4;
typedef __attribute__((ext_vector_type(16))) float f32x16;

__device__ __forceinline__ float selu_fast(float x) {
  const float scale = 1.0507009873554805f;
  const float alpha = 1.6732632423543772f;
  float e = exp2f(x * 1.44269504088896f);     // v_exp_f32; err ~1e-7 abs
  float neg = alpha * (e - 1.0f);
  return scale * (x > 0.0f ? x : neg);
}

__device__ __forceinline__ unsigned int bf16u(float x) {
  __hip_bfloat16 h = __float2bfloat16(x);     // RNE, matches prior rounds
  return (unsigned int)*reinterpret_cast<unsigned short*>(&h);
}

// ---------------- prep: W -> fragment-linear bf16 (B-operand order, r16) -----
__global__ __launch_bounds__(256) void prep_kernel(
    const float* __restrict__ W0, unsigned int* __restrict__ Wf0,
    const float* __restrict__ W1, unsigned int* __restrict__ Wf1,
    const float* __restrict__ W2, unsigned int* __restrict__ Wf2,
    const float* __restrict__ W3, unsigned int* __restrict__ Wf3,
    const float* __restrict__ Wout, unsigned int* __restrict__ WfO) {
  __shared__ float tile[32][33];
  const int t = blockIdx.x;
  const float* W;
  unsigned int* Wf;
  int N, TS, kbt, nbt;
  if (t < 16)        { W = W0;   Wf = Wf0; N = 512;  TS = 1;  kbt = 0;       nbt = t; }
  else if (t < 272)  { int u = t - 16;  W = W1;   Wf = Wf1; N = 512;  TS = 16; kbt = u & 15; nbt = u >> 4; }
  else if (t < 528)  { int u = t - 272; W = W2;   Wf = Wf2; N = 512;  TS = 16; kbt = u & 15; nbt = u >> 4; }
  else if (t < 784)  { int u = t - 528; W = W3;   Wf = Wf3; N = 512;  TS = 16; kbt = u & 15; nbt = u >> 4; }
  else               { int u = t - 784; W = Wout; Wf = WfO; N = 1024; TS = 16; kbt = u & 15; nbt = u >> 4; }
  const int kb32 = kbt * 32, nb32 = nbt * 32;
  const int tx = threadIdx.x & 31, ty = threadIdx.x >> 5;
  #pragma unroll
  for (int rr = 0; rr < 4; ++rr) {
    int kl = ty + rr * 8;
    tile[kl][tx] = W[(size_t)(kb32 + kl) * N + nb32 + tx];
  }
  __syncthreads();
  const int cbb = threadIdx.x >> 7;
  const int rest = threadIdx.x & 127;
  const int l = rest >> 1;
  const int wjh = rest & 1;
  const int cb = 2 * nbt + cbb;
  unsigned int wv[2];
  #pragma unroll
  for (int m = 0; m < 2; ++m) {
    int wj = wjh * 2 + m;
    int kl = (l >> 4) * 8 + wj * 2;
    int nl = cbb * 16 + (l & 15);
    wv[m] = bf16u(tile[kl][nl]) | (bf16u(tile[kl + 1][nl]) << 16);
  }
  size_t widx = ((size_t)(cb * TS + kbt) * 64 + l) * 4 + wjh * 2;
  *reinterpret_cast<uint2*>(Wf + widx) = make_uint2(wv[0], wv[1]);
}

// ---------------- fused MLP: 32 rows/block, 512 threads (8 waves) ------------
// FINAL (r25, best measured: 106.1us total, fused_mlp 77us).
// Block-size sweep complete: 1024thr=91us, 512thr=77us, 256thr=97us (VGPR
// blowup). K-loop: depth-1 prefetch under unroll 2 (pipelining closed after
// r18/r19 spills). Hidden layers: 2 passes accumulated (acc[2][2][2], static
// indices) before ONE barrier -> in-place act buffer safe.
template<int K>
__device__ __forceinline__ void run_hidden(
    const short8* __restrict__ Wf,
    const float* __restrict__ Wlast,
    const float* __restrict__ bias,
    char* actBuf,
    const float* tsl, int w, int lane) {
  constexpr int TS = K / 32;
  constexpr int NKB = K / 8;
  const int colloc = lane & 15, kg = lane >> 4;
  int rbyte[2], rmask[2];
  #pragma unroll
  for (int i = 0; i < 2; ++i) {
    int r = i * 16 + colloc;          // A-frag row (verified bijection)
    rbyte[i] = r * 1024;
    rmask[i] = r & (NKB - 1);
  }
  f32x4 acc[2][2][2] = {};
  #pragma unroll
  for (int pass = 0; pass < 2; ++pass) {
    const int wb = pass * 256 + w * 32;
    const int cb0 = wb >> 4;
    short8 acur[2], bcur0, bcur1;
    bcur0 = Wf[(size_t)(cb0 * TS) * 64 + lane];
    bcur1 = Wf[(size_t)((cb0 + 1) * TS) * 64 + lane];
    #pragma unroll
    for (int i = 0; i < 2; ++i)
      acur[i] = *reinterpret_cast<const short8*>(actBuf + rbyte[i] + ((kg ^ rmask[i]) * 16));
    #pragma unroll 2
    for (int t = 0; t < TS; ++t) {
      const int tn = (t + 1 < TS) ? (t + 1) : t;
      short8 bnx0 = Wf[(size_t)(cb0 * TS + tn) * 64 + lane];
      short8 bnx1 = Wf[(size_t)((cb0 + 1) * TS + tn) * 64 + lane];
      short8 anx[2];
      #pragma unroll
      for (int i = 0; i < 2; ++i)
        anx[i] = *reinterpret_cast<const short8*>(actBuf + rbyte[i] + (((tn * 4 + kg) ^ rmask[i]) * 16));
      #pragma unroll
      for (int i = 0; i < 2; ++i) {
        acc[pass][i][0] = __builtin_amdgcn_mfma_f32_16x16x32_bf16(acur[i], bcur0, acc[pass][i][0], 0, 0, 0);
        acc[pass][i][1] = __builtin_amdgcn_mfma_f32_16x16x32_bf16(acur[i], bcur1, acc[pass][i][1], 0, 0, 0);
      }
      #pragma unroll
      for (int i = 0; i < 2; ++i) acur[i] = anx[i];
      bcur0 = bnx0; bcur1 = bnx1;
    }
  }
  // ALL reads of actBuf complete block-wide before ANY write
  __syncthreads();
  #pragma unroll
  for (int pass = 0; pass < 2; ++pass) {
    const int wb = pass * 256 + w * 32;
    float wl[2], bb[2];
    #pragma unroll
    for (int c = 0; c < 2; ++c) {
      int col = wb + c * 16 + colloc;
      wl[c] = Wlast[col];
      bb[c] = bias[col];
    }
    #pragma unroll
    for (int i = 0; i < 2; ++i) {
      #pragma unroll
      for (int e = 0; e < 4; ++e) {
        int row = i * 16 + kg * 4 + e;   // D-layout row (verified)
        float tv = tsl[row];
        #pragma unroll
        for (int c = 0; c < 2; ++c) {
          float v = acc[pass][i][c][e] + tv * wl[c] + bb[c];
          v = selu_fast(v);
          int col = wb + c * 16 + colloc;
          int off = row * 1024 + (((col >> 3) ^ (row & 63)) * 16) + (col & 7) * 2;
          *reinterpret_cast<unsigned short*>(actBuf + off) = (unsigned short)bf16u(v);
        }
      }
    }
  }
}

// final layer: N=1024, 4 passes, clip + pair-pack global store (no hazard)
__device__ __forceinline__ void run_out(
    const short8* __restrict__ Wf,
    const float* __restrict__ Wlast,
    const float* __restrict__ bias,
    const char* actBuf,
    __hip_bfloat16* __restrict__ gOut, int rowbase,
    const float* tsl, int w, int lane) {
  constexpr int K = 512, TS = K / 32, NKB = K / 8;
  const int colloc = lane & 15, kg = lane >> 4;
  int rbyte[2], rmask[2];
  #pragma unroll
  for (int i = 0; i < 2; ++i) {
    int r = i * 16 + colloc;
    rbyte[i] = r * 1024;
    rmask[i] = r & (NKB - 1);
  }
  #pragma unroll 1
  for (int pass = 0; pass < 4; ++pass) {
    const int wb = pass * 256 + w * 32;
    const int cb0 = wb >> 4;
    f32x4 acc[2][2] = {};
    short8 acur[2], bcur0, bcur1;
    bcur0 = Wf[(size_t)(cb0 * TS) * 64 + lane];
    bcur1 = Wf[(size_t)((cb0 + 1) * TS) * 64 + lane];
    #pragma unroll
    for (int i = 0; i < 2; ++i)
      acur[i] = *reinterpret_cast<const short8*>(actBuf + rbyte[i] + ((kg ^ rmask[i]) * 16));
    #pragma unroll 2
    for (int t = 0; t < TS; ++t) {
      const int tn = (t + 1 < TS) ? (t + 1) : t;
      short8 bnx0 = Wf[(size_t)(cb0 * TS + tn) * 64 + lane];
      short8 bnx1 = Wf[(size_t)((cb0 + 1) * TS + tn) * 64 + lane];
      short8 anx[2];
      #pragma unroll
      for (int i = 0; i < 2; ++i)
        anx[i] = *reinterpret_cast<const short8*>(actBuf + rbyte[i] + (((tn * 4 + kg) ^ rmask[i]) * 16));
      #pragma unroll
      for (int i = 0; i < 2; ++i) {
        acc[i][0] = __builtin_amdgcn_mfma_f32_16x16x32_bf16(acur[i], bcur0, acc[i][0], 0, 0, 0);
        acc[i][1] = __builtin_amdgcn_mfma_f32_16x16x32_bf16(acur[i], bcur1, acc[i][1], 0, 0, 0);
      }
      #pragma unroll
      for (int i = 0; i < 2; ++i) acur[i] = anx[i];
      bcur0 = bnx0; bcur1 = bnx1;
    }
    float wl[2], bb[2];
    #pragma unroll
    for (int c = 0; c < 2; ++c) {
      int col = wb + c * 16 + colloc;
      wl[c] = Wlast[col];
      bb[c] = bias[col];
    }
    #pragma unroll
    for (int i = 0; i < 2; ++i) {
      #pragma unroll
      for (int e = 0; e < 4; ++e) {
        int row = i * 16 + kg * 4 + e;
        float tv = tsl[row];
        #pragma unroll
        for (int c = 0; c < 2; ++c) {
          float v = acc[i][c][e] + tv * wl[c] + bb[c];
          v = fminf(fmaxf(v, -20.f), 20.f);
          float o = __shfl_xor(v, 1);
          unsigned int me = bf16u(v), ot = bf16u(o);
          unsigned int pw = (colloc & 1) ? ((me << 16) | ot) : ((ot << 16) | me);
          const bool iwrite = ((colloc & 1) == (e >> 1));
          int col0 = wb + c * 16 + (colloc & ~1);
          if (iwrite) {
            size_t off = (size_t)(rowbase + row) * 1024 + col0;
            *reinterpret_cast<unsigned int*>(
                reinterpret_cast<char*>(gOut) + off * 2) = pw;
          }
        }
      }
    }
  }
}

__global__ __launch_bounds__(512) void fused_mlp_kernel(
    const float* __restrict__ p,
    const float* __restrict__ tvec,
    const short8* Wf0, const short8* Wf1, const short8* Wf2,
    const short8* Wf3, const short8* WfO,
    const float* W0l, const float* b0,
    const float* W1l, const float* b1,
    const float* W2l, const float* b2,
    const float* W3l, const float* b3,
    const float* WOl, const float* bO,
    __hip_bfloat16* __restrict__ flatb) {
  __shared__ char buf[32768];
  __shared__ float tsl[32];
  const int tid = threadIdx.x;
  const int w = tid >> 6, lane = tid & 63;
  const int rowbase = blockIdx.x * 32;

  if (tid < 32) tsl[tid] = tvec[rowbase + tid];
  if (tid < 256) {  // stage p -> buf (K=32 layout, NKB=4 swizzle)
    const int r = tid >> 3, g = tid & 7;
    float4 v = *reinterpret_cast<const float4*>(p + (size_t)(rowbase + r) * 32 + g * 4);
    unsigned int lo = bf16u(v.x) | (bf16u(v.y) << 16);
    unsigned int hi = bf16u(v.z) | (bf16u(v.w) << 16);
    int off = r * 1024 + (((g >> 1) ^ (r & 3)) * 16) + (g & 1) * 8;
    *reinterpret_cast<uint2*>(buf + off) = make_uint2(lo, hi);
  }
  __syncthreads();

  run_hidden<32>(Wf0, W0l, b0, buf, tsl, w, lane);
  __syncthreads();
  run_hidden<512>(Wf1, W1l, b1, buf, tsl, w, lane);
  __syncthreads();
  run_hidden<512>(Wf2, W2l, b2, buf, tsl, w, lane);
  __syncthreads();
  run_hidden<512>(Wf3, W3l, b3, buf, tsl, w, lane);
  __syncthreads();
  run_out(WfO, WOl, bO, buf, flatb, rowbase, tsl, w, lane);
}

// ---------------- expm: transposed chain, 2 matrices/wave ILP (r11, frozen) --
#define WAITLDS asm volatile("s_waitcnt lgkmcnt(0)" ::: "memory")

__device__ __forceinline__ unsigned int bf16r(float x) {
  return (__float_as_uint(x) + 0x8000u) >> 16;
}

__device__ __forceinline__ void d2b_lean(const float (&X)[16], int G, short8 (&bfr)[2]) {
  float rcv[8];
  #pragma unroll
  for (int j = 0; j < 8; ++j) {
    const int hp = j >> 2, tt = j & 3;
    float snd = G ? X[8 * hp + tt] : X[8 * hp + 4 + tt];
    rcv[j] = __shfl_xor(snd, 32);
  }
  #pragma unroll
  for (int h = 0; h < 2; ++h) {
    float r8v[8];
    #pragma unroll
    for (int j2 = 0; j2 < 8; ++j2) {
      if (j2 < 4) r8v[j2] = G ? rcv[4 * h + j2] : X[8 * h + j2];
      else        r8v[j2] = G ? X[8 * h + j2] : rcv[4 * h + j2 - 4];
    }
    union { short8 s8; unsigned int u[4]; } bu;
    #pragma unroll
    for (int j = 0; j < 4; ++j)
      bu.u[j] = bf16r(r8v[2 * j]) | (bf16r(r8v[2 * j + 1]) << 16);
    bfr[h] = bu.s8;
  }
}

__device__ __forceinline__ void d2b_split_lean(const float (&X)[16], int G,
                                               short8 (&bh)[2], short8 (&bl)[2]) {
  float rcv[8];
  #pragma unroll
  for (int j = 0; j < 8; ++j) {
    const int hp = j >> 2, tt = j & 3;
    float snd = G ? X[8 * hp + tt] : X[8 * hp + 4 + tt];
    rcv[j] = __shfl_xor(snd, 32);
  }
  #pragma unroll
  for (int h = 0; h < 2; ++h) {
    float r8v[8];
    #pragma unroll
    for (int j2 = 0; j2 < 8; ++j2) {
      if (j2 < 4) r8v[j2] = G ? rcv[4 * h + j2] : X[8 * h + j2];
      else        r8v[j2] = G ? X[8 * h + j2] : rcv[4 * h + j2 - 4];
    }
    union { short8 s8; unsigned int u[4]; } uh, ul;
    #pragma unroll
    for (int j = 0; j < 4; ++j) {
      unsigned int b0 = __float_as_uint(r8v[2 * j]) & 0xFFFF0000u;
      unsigned int b1 = __float_as_uint(r8v[2 * j + 1]) & 0xFFFF0000u;
      float l0 = r8v[2 * j] - __uint_as_float(b0);
      float l1 = r8v[2 * j + 1] - __uint_as_float(b1);
      uh.u[j] = (b0 >> 16) | b1;
      ul.u[j] = bf16r(l0) | (bf16r(l1) << 16);
    }
    bh[h] = uh.s8;
    bl[h] = ul.s8;
  }
}

union u4s8 { uint4 u4; short8 s8; unsigned int u[4]; };

__global__ __launch_bounds__(256) void expm_ilp2_kernel(
    const __hip_bfloat16* __restrict__ flat,
    const float* __restrict__ q,
    const float* __restrict__ dtp,
    float* __restrict__ out_q,
    float* __restrict__ out_dlogp) {
  __shared__ __align__(16) unsigned int SL[4][2][16][33];
  const int tid = threadIdx.x;
  const int w = tid >> 6, lane = tid & 63;
  const int C = lane & 31, G = lane >> 5;
  const int m0 = blockIdx.x * 8 + w * 2;
  const float dt = dtp[0];

  u4s8 t0[2], t1[2];
  float E[2][16];
  float uu[2];
  int nv[2];

  #pragma unroll
  for (int mm = 0; mm < 2; ++mm) {
    const int m = m0 + mm;
    const uint4* fm = reinterpret_cast<const uint4*>(flat + (size_t)m * 1024);
    uint4 v0 = fm[lane];
    uint4 v1 = fm[lane + 64];
    {
      const int r0 = lane >> 2, kpb = (lane & 3) * 4;
      SL[w][mm][kpb + 0][r0] = v0.x; SL[w][mm][kpb + 1][r0] = v0.y;
      SL[w][mm][kpb + 2][r0] = v0.z; SL[w][mm][kpb + 3][r0] = v0.w;
      SL[w][mm][kpb + 0][r0 + 16] = v1.x; SL[w][mm][kpb + 1][r0 + 16] = v1.y;
      SL[w][mm][kpb + 2][r0 + 16] = v1.z; SL[w][mm][kpb + 3][r0 + 16] = v1.w;
    }
    {
      const char* base = reinterpret_cast<const char*>(flat) + (size_t)m * 2048 + C * 64 + G * 16;
      t0[mm].u4 = *reinterpret_cast<const uint4*>(base);
      t1[mm].u4 = *reinterpret_cast<const uint4*>(base + 32);
    }

    float sa = 0.f;
    #pragma unroll
    for (int i = 0; i < 4; ++i) {
      sa += fabsf(__uint_as_float(t0[mm].u[i] << 16)) + fabsf(__uint_as_float(t0[mm].u[i] & 0xFFFF0000u));
      sa += fabsf(__uint_as_float(t1[mm].u[i] << 16)) + fabsf(__uint_as_float(t1[mm].u[i] & 0xFFFF0000u));
    }
    sa += __shfl_xor(sa, 32);
    float nrm = sa;
    #pragma unroll
    for (int off = 1; off < 32; off <<= 1) nrm = fmaxf(nrm, __shfl_xor(nrm, off));

    int s = 0;
    float anrm = dt * nrm;
    if (anrm > 1.0f) {
      s = (int)ceilf(log2f(anrm));
      s = s < 1 ? 1 : (s > 6 ? 6 : s);
    }
    nv[mm] = 1 << s;
    const float u = dt * exp2f(-(float)s);
    uu[mm] = u;

    unsigned int pt0[4], pt1[4];
    #pragma unroll
    for (int d = 0; d < 4; ++d) {
      pt0[d] = (unsigned int)__shfl_xor((int)t0[mm].u[d], 32);
      pt1[d] = (unsigned int)__shfl_xor((int)t1[mm].u[d], 32);
    }
    float tr = 0.f;
    #pragma unroll
    for (int j = 0; j < 4; ++j) {
      #pragma unroll
      for (int e2 = 0; e2 < 4; ++e2) {
        const int i = 4 * j + e2;
        const int rd = e2 + 8 * j + 4 * G;
        const bool own = ((j & 1) == G);
        unsigned int dwO, dwP;
        if ((e2 >> 1) == 0) {
          dwO = G ? ((j < 2) ? t0[mm].u[2] : t1[mm].u[2]) : ((j < 2) ? t0[mm].u[0] : t1[mm].u[0]);
          dwP = G ? ((j < 2) ? pt0[2] : pt1[2]) : ((j < 2) ? pt0[0] : pt1[0]);
        } else {
          dwO = G ? ((j < 2) ? t0[mm].u[3] : t1[mm].u[3]) : ((j < 2) ? t0[mm].u[1] : t1[mm].u[1]);
          dwP = G ? ((j < 2) ? pt0[3] : pt1[3]) : ((j < 2) ? pt0[1] : pt1[1]);
        }
        unsigned int dw = own ? dwO : dwP;
        unsigned int h16 = (e2 & 1) ? (dw >> 16) : (dw & 0xFFFFu);
        float mv = __uint_as_float(h16 << 16);
        float dI = (rd == C) ? 1.0f : 0.0f;
        E[mm][i] = dI + u * mv;
        tr += dI * mv;
      }
    }
    #pragma unroll
    for (int off = 1; off < 64; off <<= 1) tr += __shfl_xor(tr, off);
    if (lane == 0) out_dlogp[m] = dt * tr;
  }

  WAITLDS;

  short8 Mfr[2][2];
  {
    const unsigned int selpat = (C & 1) ? 0x07060302u : 0x05040100u;
    #pragma unroll
    for (int mm = 0; mm < 2; ++mm) {
      #pragma unroll
      for (int h = 0; h < 2; ++h) {
        unsigned int rr[8];
        #pragma unroll
        for (int e = 0; e < 8; ++e) rr[e] = SL[w][mm][C >> 1][16 * h + 8 * G + e];
        union { short8 s8; unsigned int u[4]; } mu;
        #pragma unroll
        for (int j = 0; j < 4; ++j)
          mu.u[j] = __builtin_amdgcn_perm(rr[2 * j + 1], rr[2 * j], selpat);
        Mfr[mm][h] = mu.s8;
      }
    }
  }

  float Qc[2][16];
  float ck[2];
  #pragma unroll
  for (int mm = 0; mm < 2; ++mm) {
    ck[mm] = uu[mm] * uu[mm] * 0.5f;
    f32x16 acc = {};
    acc = __builtin_amdgcn_mfma_f32_32x32x16_bf16(Mfr[mm][0], t0[mm].s8, acc, 0, 0, 0);
    acc = __builtin_amdgcn_mfma_f32_32x32x16_bf16(Mfr[mm][1], t1[mm].s8, acc, 0, 0, 0);
    #pragma unroll
    for (int i = 0; i < 16; ++i) { Qc[mm][i] = acc[i]; E[mm][i] += ck[mm] * acc[i]; }
  }
  #pragma unroll
  for (int k = 3; k <= 6; ++k) {
    #pragma unroll
    for (int mm = 0; mm < 2; ++mm) {
      short8 bfr[2];
      d2b_lean(Qc[mm], G, bfr);
      f32x16 acc = {};
      acc = __builtin_amdgcn_mfma_f32_32x32x16_bf16(Mfr[mm][0], bfr[0], acc, 0, 0, 0);
      acc = __builtin_amdgcn_mfma_f32_32x32x16_bf16(Mfr[mm][1], bfr[1], acc, 0, 0, 0);
      ck[mm] *= uu[mm] * (1.0f / (float)k);
      #pragma unroll
      for (int i = 0; i < 16; ++i) { Qc[mm][i] = acc[i]; E[mm][i] += ck[mm] * acc[i]; }
    }
  }

  short8 beh[2][2], bel[2][2];
  #pragma unroll
  for (int mm = 0; mm < 2; ++mm)
    d2b_split_lean(E[mm], G, beh[mm], bel[mm]);

  float qv[2];
  qv[0] = q[(size_t)m0 * 32 + C];
  qv[1] = q[(size_t)(m0 + 1) * 32 + C];
  const int nvmax = nv[0] > nv[1] ? nv[0] : nv[1];
  #pragma unroll 1
  for (int it = 0; it < nvmax; ++it) {
    #pragma unroll
    for (int mm = 0; mm < 2; ++mm) {
      unsigned int hb = __float_as_uint(qv[mm]) & 0xFFFF0000u;
      float lof = qv[mm] - __uint_as_float(hb);
      unsigned int pw = (hb >> 16) | (bf16r(lof) << 16);
      short8 vh[2], vl[2];
      #pragma unroll
      for (int h = 0; h < 2; ++h) {
        unsigned int g[8];
        #pragma unroll
        for (int e = 0; e < 8; ++e)
          g[e] = (unsigned int)__shfl((int)pw, 16 * h + 8 * G + e);
        union { short8 s8; unsigned int u[4]; } uh, ul;
        #pragma unroll
        for (int j = 0; j < 4; ++j) {
          uh.u[j] = __builtin_amdgcn_perm(g[2 * j + 1], g[2 * j], 0x05040100u);
          ul.u[j] = __builtin_amdgcn_perm(g[2 * j + 1], g[2 * j], 0x07060302u);
        }
        vh[h] = uh.s8;
        vl[h] = ul.s8;
      }
      f32x16 acc = {};
      acc = __builtin_amdgcn_mfma_f32_32x32x16_bf16(vh[0], beh[mm][0], acc, 0, 0, 0);
      acc = __builtin_amdgcn_mfma_f32_32x32x16_bf16(vh[1], beh[mm][1], acc, 0, 0, 0);
      acc = __builtin_amdgcn_mfma_f32_32x32x16_bf16(vl[0], beh[mm][0], acc, 0, 0, 0);
      acc = __builtin_amdgcn_mfma_f32_32x32x16_bf16(vl[1], beh[mm][1], acc, 0, 0, 0);
      acc = __builtin_amdgcn_mfma_f32_32x32x16_bf16(vh[0], bel[mm][0], acc, 0, 0, 0);
      acc = __builtin_amdgcn_mfma_f32_32x32x16_bf16(vh[1], bel[mm][1], acc, 0, 0, 0);
      qv[mm] = (it < nv[mm]) ? acc[0] : qv[mm];
    }
  }
  if (G == 0) {
    out_q[(size_t)m0 * 32 + C] = qv[0];
    out_q[(size_t)(m0 + 1) * 32 + C] = qv[1];
  }
}

extern "C" void kernel_launch(void* const* d_in, const int* in_sizes, int n_in,
                              void* d_out, int out_size, void* d_ws, size_t ws_size,
                              hipStream_t stream) {
  const float* q    = (const float*)d_in[0];
  const float* p    = (const float*)d_in[1];
  const float* t    = (const float*)d_in[2];
  const float* dt   = (const float*)d_in[3];
  const float* W0   = (const float*)d_in[4];
  const float* b0   = (const float*)d_in[5];
  const float* W1   = (const float*)d_in[6];
  const float* b1   = (const float*)d_in[7];
  const float* W2   = (const float*)d_in[8];
  const float* b2   = (const float*)d_in[9];
  const float* W3   = (const float*)d_in[10];
  const float* b3   = (const float*)d_in[11];
  const float* Wout = (const float*)d_in[12];
  const float* bout = (const float*)d_in[13];

  // ws layout: flatb (bf16 B*1024), then fragment-linear weights (u32)
  char* ws = (char*)d_ws;
  __hip_bfloat16* flatb = (__hip_bfloat16*)ws;              // 32 MB
  unsigned int* Wf0 = (unsigned int*)(ws + (size_t)BTOT * 1024 * 2);
  unsigned int* Wf1 = Wf0 + 32 * 512 / 2;
  unsigned int* Wf2 = Wf1 + 512 * 512 / 2;
  unsigned int* Wf3 = Wf2 + 512 * 512 / 2;
  unsigned int* WfO = Wf3 + 512 * 512 / 2;

  prep_kernel<<<1296, 256, 0, stream>>>(W0, Wf0, W1, Wf1, W2, Wf2, W3, Wf3,
                                        Wout, WfO);

  fused_mlp_kernel<<<512, 512, 0, stream>>>(
      p, t,
      (const short8*)Wf0, (const short8*)Wf1, (const short8*)Wf2,
      (const short8*)Wf3, (const short8*)WfO,
      W0 + 32 * 512, b0, W1 + 512 * 512, b1, W2 + 512 * 512, b2,
      W3 + 512 * 512, b3, Wout + 512 * 1024, bout, flatb);

  float* out_q     = (float*)d_out;
  float* out_dlogp = out_q + (size_t)BTOT * 32;
  expm_ilp2_kernel<<<BTOT / 8, 256, 0, stream>>>(flatb, q, dt, out_q, out_dlogp);
}